// Round 3
// baseline (1068.667 us; speedup 1.0000x reference)
//
#include <hip/hip_runtime.h>
#include <stdint.h>

typedef float f32x4 __attribute__((ext_vector_type(4)));
typedef float f32x2 __attribute__((ext_vector_type(2)));
typedef __bf16 bf16x8 __attribute__((ext_vector_type(8)));
typedef __bf16 bf16x4 __attribute__((ext_vector_type(4)));

#define SEQ 50
#define TDEC 60

static __device__ __forceinline__ float ex2(float x){return __builtin_amdgcn_exp2f(x);}
static __device__ __forceinline__ float frcp_(float x){return __builtin_amdgcn_rcpf(x);}
static __device__ __forceinline__ __bf16 bfc(float x){return (__bf16)x;}

// Software-pipelined (same structure as prev round). ONE change: launch_bounds
// (256,3)->(256,2). Prev round: VGPR_Count=84 vs ~160 live (24 bf16x8 weights
// = 96 VGPR + 2x acc + cs) -> allocator spilled ~half the weight frags to
// scratch; 282 MB/dispatch spill stores (WRITE 298MB vs 15.7MB payload) and
// L2-latency scratch reloads inside every MFMA dependency chain. 256-VGPR cap
// lets weights stay resident; occupancy follows ACTUAL vgpr use (<=170 -> still
// 3 blocks/CU).
__global__ __launch_bounds__(256,2) void lstm_s2s(
    const float* __restrict__ hist,
    const float* __restrict__ eWih0, const float* __restrict__ eWhh0,
    const float* __restrict__ ebih0, const float* __restrict__ ebhh0,
    const float* __restrict__ eWih1, const float* __restrict__ eWhh1,
    const float* __restrict__ ebih1, const float* __restrict__ ebhh1,
    const float* __restrict__ dWih0, const float* __restrict__ dWhh0,
    const float* __restrict__ dbih0, const float* __restrict__ dbhh0,
    const float* __restrict__ dWih1, const float* __restrict__ dWhh1,
    const float* __restrict__ dbih1, const float* __restrict__ dbhh1,
    const float* __restrict__ linW, const float* __restrict__ linb,
    const float* __restrict__ stok,
    float* __restrict__ out)
{
  __shared__ __bf16 xch[SEQ*16*8];     // [t][row16][8] (6 real, slot6=1.0 bias, slot7=0)
  __shared__ __bf16 hb0[2][1024];      // [kc][q_r][m16][j8], double-buffered
  __shared__ __bf16 hb1[2][1024];
  __shared__ __bf16 wx0s[4*4*17*8];    // L0 x-weight A-frags [w][g][row17][8], row16=0
  __shared__ float  bC1[256];          // L1 bias C-init [w][g][q][r] f32 (pre-scaled)
  __shared__ __bf16 wlc[2*3*4*8];      // head A-frags [kc][row(0,1,zero)][q][8]
  __shared__ float  obf[16*124];       // output staging [row16][120+4pad]

  const int tid = threadIdx.x;
  const int lane = tid & 63;
  const int w = tid >> 6;
  const int c = lane & 15;
  const int q = lane >> 4;
  const int rsel = (q == 0) ? c : 16;          // zero-row redirect for q>0
  const long rowbase = (long)blockIdx.x * 16;
  const float* eg = hist + rowbase * 3000;     // agent-0 slice; 3000 = A*S*IN

  union { f32x4 f; bf16x8 h; } Z;
  Z.f[0]=0.f; Z.f[1]=0.f; Z.f[2]=0.f; Z.f[3]=0.f;
  const f32x4 zero4 = Z.f;
  const bf16x8 zfrag = Z.h;

  const float GS[4] = {-1.442695041f,-1.442695041f,2.885390082f,-1.442695041f};

  // ---- prologue staging ----
  for (int i = tid; i < 16*300; i += 256) {
    int row = i / 300, o = i - row*300;
    int t = o / 6, k = o - t*6;
    xch[(t*16+row)*8 + k] = bfc(eg[row*3000 + o]);
  }
  for (int i = tid; i < 16*SEQ; i += 256) {
    xch[i*8+6] = (__bf16)1.0f;
    xch[i*8+7] = (__bf16)0.0f;
  }
  for (int i = tid; i < 512; i += 256) {
    ((uint32_t*)hb0[0])[i] = 0u;
    ((uint32_t*)hb1[0])[i] = 0u;
  }

  auto stageWx0 = [&](const float* W, int Kin, const float* bi, const float* bh) {
    for (int i = tid; i < 272; i += 256) {
      int w2 = i / 68, rem = i - w2*68;
      int g = rem / 17, row = rem - g*17;
      __bf16* dst = wx0s + i*8;
      if (row < 16) {
        int gate = (g*4 + w2)*16 + row;
        float gs = (g==2) ? 2.885390082f : -1.442695041f;
        for (int j = 0; j < 8; ++j) {
          float v = 0.f;
          if (j < Kin) v = W[gate*Kin + j];
          else if (j == 6) v = bi[gate] + bh[gate];
          dst[j] = bfc(gs*v);
        }
      } else {
        for (int j = 0; j < 8; ++j) dst[j] = (__bf16)0.f;
      }
    }
  };
  auto stageBc1 = [&](const float* bi, const float* bh) {
    for (int i = tid; i < 256; i += 256) {
      int w2 = i >> 6, g = (i >> 4) & 3, q2 = (i >> 2) & 3, r = i & 3;
      int gate = (g*4 + w2)*16 + q2*4 + r;
      float gs = (g==2) ? 2.885390082f : -1.442695041f;
      bC1[i] = gs*(bi[gate] + bh[gate]);
    }
  };

  bf16x8 whL0[4][2], wxL1[4][2], whL1[4][2];
  auto loadFull = [&](const float* W, bf16x8 (*dst)[2]) {
#pragma unroll
    for (int g = 0; g < 4; ++g)
#pragma unroll
      for (int kc = 0; kc < 2; ++kc) {
        const float* p = W + ((g*4 + w)*16 + c)*64 + kc*32 + q*8;
        f32x4 a = *(const f32x4*)p;
        f32x4 b = *(const f32x4*)(p + 4);
        bf16x8 f;
        f[0]=bfc(GS[g]*a[0]); f[1]=bfc(GS[g]*a[1]);
        f[2]=bfc(GS[g]*a[2]); f[3]=bfc(GS[g]*a[3]);
        f[4]=bfc(GS[g]*b[0]); f[5]=bfc(GS[g]*b[1]);
        f[6]=bfc(GS[g]*b[2]); f[7]=bfc(GS[g]*b[3]);
        dst[g][kc] = f;
      }
  };

  // epilogue write address: hidden u = 16w + q*4 + r, r=0..3 contiguous j
  const int wconst = (w>>1)*512 + (((w&1)<<1) | (q>>1))*128 + c*8 + (q&1)*4;

  float cs0[4], cs1[4];
#pragma unroll
  for (int i = 0; i < 4; ++i) { cs0[i] = 0.f; cs1[i] = 0.f; }

  auto epilogue = [&](f32x4* a, float* cs, __bf16* hnxt) {
    bf16x4 hv;
#pragma unroll
    for (int r = 0; r < 4; ++r) {
      float eI = ex2(a[0][r]);          // e^{-i}
      float eF = ex2(a[1][r]);          // e^{-f}
      float eG = ex2(a[2][r]);          // e^{2g}
      float eO = ex2(a[3][r]);          // e^{-o}
      float P  = (1.f+eI)*(eG+1.f);
      float tt = 1.f+eF;
      float D  = frcp_(tt*P);
      float c2 = (cs[r]*P + (eG-1.f)*tt)*D;
      float eC = ex2(2.885390082f*c2);
      float h2 = (eC-1.f)*frcp_((1.f+eO)*(eC+1.f));
      cs[r] = c2;
      hv[r] = bfc(h2);
    }
    *(bf16x4*)(hnxt + wconst) = hv;     // one 8B packed write, NO barrier here
  };

  // ---- encoder ----
  stageWx0(eWih0, 6, ebih0, ebhh0);
  stageBc1(ebih1, ebhh1);
  loadFull(eWhh0, whL0);
  loadFull(eWih1, wxL1);
  loadFull(eWhh1, whL1);
  __syncthreads();

  f32x4 acc0[4];
  { // t=0 cellP: h0_{-1}=0 -> x-MFMA only
    bf16x8 xf = zfrag;
    if (q == 0) xf = *(const bf16x8*)(xch + c*8);
#pragma unroll
    for (int g = 0; g < 4; ++g) {
      bf16x8 wxf = *(const bf16x8*)(wx0s + ((w*4+g)*17 + rsel)*8);
      acc0[g] = __builtin_amdgcn_mfma_f32_16x16x32_bf16(wxf, xf, zero4, 0,0,0);
    }
  }

  int pc = 0;
#pragma unroll 1
  for (int t = 0; t < SEQ; ++t) {
    f32x4 acc1[4];
    { // interval 1: L1 h-part MFMAs (indep of epilogue0) overlap epilogue0 VALU
      const __bf16* h1p = hb1[pc];
      bf16x8 hf0 = *(const bf16x8*)(h1p + lane*8);
      bf16x8 hf1 = *(const bf16x8*)(h1p + 512 + lane*8);
#pragma unroll
      for (int g = 0; g < 4; ++g) {
        f32x4 bi4 = *(const f32x4*)(bC1 + w*64 + g*16 + q*4);
        acc1[g] = __builtin_amdgcn_mfma_f32_16x16x32_bf16(whL1[g][0], hf0, bi4, 0,0,0);
      }
#pragma unroll
      for (int g = 0; g < 4; ++g)
        acc1[g] = __builtin_amdgcn_mfma_f32_16x16x32_bf16(whL1[g][1], hf1, acc1[g], 0,0,0);
    }
    epilogue(acc0, cs0, hb0[pc^1]);     // -> h0_t
    __syncthreads();
    { // interval 2: finish L1, then prefire next step's full L0 before barrier
      const __bf16* h0n = hb0[pc^1];
      bf16x8 xf0 = *(const bf16x8*)(h0n + lane*8);
      bf16x8 xf1 = *(const bf16x8*)(h0n + 512 + lane*8);
#pragma unroll
      for (int g = 0; g < 4; ++g)
        acc1[g] = __builtin_amdgcn_mfma_f32_16x16x32_bf16(wxL1[g][0], xf0, acc1[g], 0,0,0);
#pragma unroll
      for (int g = 0; g < 4; ++g)
        acc1[g] = __builtin_amdgcn_mfma_f32_16x16x32_bf16(wxL1[g][1], xf1, acc1[g], 0,0,0);
      epilogue(acc1, cs1, hb1[pc^1]);   // -> h1_t
      if (t + 1 < SEQ) {                // next-step L0: h0_t already in regs/LDS
        bf16x8 xf = zfrag;
        if (q == 0) xf = *(const bf16x8*)(xch + (t+1)*128 + c*8);
#pragma unroll
        for (int g = 0; g < 4; ++g) {
          bf16x8 wxf = *(const bf16x8*)(wx0s + ((w*4+g)*17 + rsel)*8);
          acc0[g] = __builtin_amdgcn_mfma_f32_16x16x32_bf16(wxf, xf, zero4, 0,0,0);
        }
#pragma unroll
        for (int g = 0; g < 4; ++g)
          acc0[g] = __builtin_amdgcn_mfma_f32_16x16x32_bf16(whL0[g][0], xf0, acc0[g], 0,0,0);
#pragma unroll
        for (int g = 0; g < 4; ++g)
          acc0[g] = __builtin_amdgcn_mfma_f32_16x16x32_bf16(whL0[g][1], xf1, acc0[g], 0,0,0);
      }
    }
    __syncthreads();
    pc ^= 1;
  }

  // ---- decoder setup ----
  stageWx0(dWih0, 2, dbih0, dbhh0);
  stageBc1(dbih1, dbhh1);
  loadFull(dWhh0, whL0);
  loadFull(dWih1, wxL1);
  loadFull(dWhh1, whL1);
  for (int i = tid; i < 24; i += 256) {
    int kc = i / 12, rem = i - kc*12;
    int row = rem / 4, q2 = rem - row*4;
    __bf16* dst = wlc + i*8;
    for (int j = 0; j < 8; ++j)
      dst[j] = (row < 2) ? bfc(linW[row*64 + kc*32 + q2*8 + j]) : (__bf16)0.f;
  }
  const float lb0 = linb[0], lb1 = linb[1];
  const float s0 = stok[0], s1 = stok[1];
  __syncthreads();

  // decoder feedback frag lives in registers (q==0 lanes carry [o0,o1,...,1,0])
  bf16x8 xdec = zfrag;
  if (q == 0) { xdec[0] = bfc(s0); xdec[1] = bfc(s1); xdec[6] = (__bf16)1.0f; }
  { // decoder prologue: acc0 for t=0 (x = start token, h = h0_enc)
    const __bf16* h0p = hb0[pc];
    bf16x8 hf0 = *(const bf16x8*)(h0p + lane*8);
    bf16x8 hf1 = *(const bf16x8*)(h0p + 512 + lane*8);
#pragma unroll
    for (int g = 0; g < 4; ++g) {
      bf16x8 wxf = *(const bf16x8*)(wx0s + ((w*4+g)*17 + rsel)*8);
      acc0[g] = __builtin_amdgcn_mfma_f32_16x16x32_bf16(wxf, xdec, zero4, 0,0,0);
    }
#pragma unroll
    for (int g = 0; g < 4; ++g)
      acc0[g] = __builtin_amdgcn_mfma_f32_16x16x32_bf16(whL0[g][0], hf0, acc0[g], 0,0,0);
#pragma unroll
    for (int g = 0; g < 4; ++g)
      acc0[g] = __builtin_amdgcn_mfma_f32_16x16x32_bf16(whL0[g][1], hf1, acc0[g], 0,0,0);
  }

  // ---- decoder ----
#pragma unroll 1
  for (int t = 0; t < TDEC; ++t) {
    f32x4 acc1[4];
    {
      const __bf16* h1p = hb1[pc];
      bf16x8 hf0 = *(const bf16x8*)(h1p + lane*8);
      bf16x8 hf1 = *(const bf16x8*)(h1p + 512 + lane*8);
#pragma unroll
      for (int g = 0; g < 4; ++g) {
        f32x4 bi4 = *(const f32x4*)(bC1 + w*64 + g*16 + q*4);
        acc1[g] = __builtin_amdgcn_mfma_f32_16x16x32_bf16(whL1[g][0], hf0, bi4, 0,0,0);
      }
#pragma unroll
      for (int g = 0; g < 4; ++g)
        acc1[g] = __builtin_amdgcn_mfma_f32_16x16x32_bf16(whL1[g][1], hf1, acc1[g], 0,0,0);
    }
    epilogue(acc0, cs0, hb0[pc^1]);
    __syncthreads();
    {
      const __bf16* h0n = hb0[pc^1];
      bf16x8 xf0 = *(const bf16x8*)(h0n + lane*8);
      bf16x8 xf1 = *(const bf16x8*)(h0n + 512 + lane*8);
#pragma unroll
      for (int g = 0; g < 4; ++g)
        acc1[g] = __builtin_amdgcn_mfma_f32_16x16x32_bf16(wxL1[g][0], xf0, acc1[g], 0,0,0);
#pragma unroll
      for (int g = 0; g < 4; ++g)
        acc1[g] = __builtin_amdgcn_mfma_f32_16x16x32_bf16(wxL1[g][1], xf1, acc1[g], 0,0,0);
      epilogue(acc1, cs1, hb1[pc^1]);
      if (t + 1 < TDEC) {               // next-step L0 h-part (x waits for head)
#pragma unroll
        for (int g = 0; g < 4; ++g)
          acc0[g] = __builtin_amdgcn_mfma_f32_16x16x32_bf16(whL0[g][0], xf0, zero4, 0,0,0);
#pragma unroll
        for (int g = 0; g < 4; ++g)
          acc0[g] = __builtin_amdgcn_mfma_f32_16x16x32_bf16(whL0[g][1], xf1, acc0[g], 0,0,0);
      }
    }
    __syncthreads();
    { // head: redundant in ALL waves -> feedback stays in registers, no 3rd barrier
      const __bf16* h1n = hb1[pc^1];
      bf16x8 xh0 = *(const bf16x8*)(h1n + lane*8);
      bf16x8 xh1 = *(const bf16x8*)(h1n + 512 + lane*8);
      int hr = (c < 2) ? c : 2;
      bf16x8 wl0 = *(const bf16x8*)(wlc + hr*32 + q*8);
      bf16x8 wl1 = *(const bf16x8*)(wlc + 96 + hr*32 + q*8);
      f32x4 oa = __builtin_amdgcn_mfma_f32_16x16x32_bf16(wl0, xh0, zero4, 0,0,0);
      oa = __builtin_amdgcn_mfma_f32_16x16x32_bf16(wl1, xh1, oa, 0,0,0);
      if (q == 0) {                     // rows m=0,1 live in quad 0, regs 0,1
        float v0 = oa[0] + lb0, v1 = oa[1] + lb1;
        if (w == 0) {
          f32x2 vv; vv[0] = v0; vv[1] = v1;
          *(f32x2*)(obf + c*124 + t*2) = vv;   // LDS staging, flushed at end
        }
        xdec[0] = bfc(v0); xdec[1] = bfc(v1);
      }
      if (t + 1 < TDEC) {               // finish next acc0 with x-MFMA
#pragma unroll
        for (int g = 0; g < 4; ++g) {
          bf16x8 wxf = *(const bf16x8*)(wx0s + ((w*4+g)*17 + rsel)*8);
          acc0[g] = __builtin_amdgcn_mfma_f32_16x16x32_bf16(wxf, xdec, acc0[g], 0,0,0);
        }
      }
    }
    pc ^= 1;
  }

  // ---- coalesced output flush ----
  __syncthreads();
  for (int i = tid; i < 480; i += 256) {
    int row = i / 30;
    int j = (i - row*30) * 4;
    f32x4 v = *(const f32x4*)(obf + row*124 + j);
    *(f32x4*)(out + rowbase*120 + i*4) = v;
  }
}

extern "C" void kernel_launch(void* const* d_in, const int* in_sizes, int n_in,
                              void* d_out, int out_size, void* d_ws, size_t ws_size,
                              hipStream_t stream) {
  (void)in_sizes; (void)n_in; (void)d_ws; (void)ws_size; (void)out_size;
  const float* p[20];
  for (int i = 0; i < 20; ++i) p[i] = (const float*)d_in[i];
  dim3 grid(2048), block(256);
  hipLaunchKernelGGL(lstm_s2s, grid, block, 0, stream,
                     p[0], p[1], p[2], p[3], p[4], p[5], p[6], p[7], p[8], p[9],
                     p[10], p[11], p[12], p[13], p[14], p[15], p[16], p[17], p[18], p[19],
                     (float*)d_out);
}

// Round 4
// 1020.152 us; speedup vs baseline: 1.0476x; 1.0476x over previous
//
#include <hip/hip_runtime.h>
#include <stdint.h>

typedef float f32x4 __attribute__((ext_vector_type(4)));
typedef float f32x2 __attribute__((ext_vector_type(2)));
typedef __bf16 bf16x8 __attribute__((ext_vector_type(8)));
typedef __bf16 bf16x4 __attribute__((ext_vector_type(4)));

#define SEQ 50
#define TDEC 60

static __device__ __forceinline__ float ex2(float x){return __builtin_amdgcn_exp2f(x);}
static __device__ __forceinline__ float frcp_(float x){return __builtin_amdgcn_rcpf(x);}
static __device__ __forceinline__ __bf16 bfc(float x){return (__bf16)x;}

// TWO independent 16-row batch groups per block (32 rows, grid 1024).
// Weight frags (96 VGPR) shared across groups; acc/cs/xdec duplicated.
// -> 2x MFMA + 2x epilogue ILP per wave, barriers-per-work halved.
// Spill fix from prev round retained (launch_bounds(256,2), weights resident).
// obf aliases xch (encoder-only vs decoder-only lifetimes).
__global__ __launch_bounds__(256,2) void lstm_s2s(
    const float* __restrict__ hist,
    const float* __restrict__ eWih0, const float* __restrict__ eWhh0,
    const float* __restrict__ ebih0, const float* __restrict__ ebhh0,
    const float* __restrict__ eWih1, const float* __restrict__ eWhh1,
    const float* __restrict__ ebih1, const float* __restrict__ ebhh1,
    const float* __restrict__ dWih0, const float* __restrict__ dWhh0,
    const float* __restrict__ dbih0, const float* __restrict__ dbhh0,
    const float* __restrict__ dWih1, const float* __restrict__ dWhh1,
    const float* __restrict__ dbih1, const float* __restrict__ dbhh1,
    const float* __restrict__ linW, const float* __restrict__ linb,
    const float* __restrict__ stok,
    float* __restrict__ out)
{
  __shared__ __bf16 xch[SEQ*32*8];     // [t][row32][8]; decoder: aliased as obf f32[32][124]
  __shared__ __bf16 hb0[2][2][1024];   // [pc][grp][kc*512 + q_r*128 + m16*8 + j8]
  __shared__ __bf16 hb1[2][2][1024];
  __shared__ __bf16 wx0s[4*4*17*8];    // L0 x-weight A-frags [w][g][row17][8], row16=0
  __shared__ float  bC1[256];          // L1 bias C-init [w][g][q][r] f32 (pre-scaled)
  __shared__ __bf16 wlc[2*3*4*8];      // head A-frags [kc][row(0,1,zero)][q][8]

  const int tid = threadIdx.x;
  const int lane = tid & 63;
  const int w = tid >> 6;
  const int c = lane & 15;
  const int q = lane >> 4;
  const int rsel = (q == 0) ? c : 16;          // zero-row redirect for q>0
  const long rowbase = (long)blockIdx.x * 32;
  const float* eg = hist + rowbase * 3000;     // agent-0 slice; 3000 = A*S*IN

  union { f32x4 f; bf16x8 h; } Z;
  Z.f[0]=0.f; Z.f[1]=0.f; Z.f[2]=0.f; Z.f[3]=0.f;
  const f32x4 zero4 = Z.f;
  const bf16x8 zfrag = Z.h;

  const float GS[4] = {-1.442695041f,-1.442695041f,2.885390082f,-1.442695041f};

  // ---- prologue staging (32 rows) ----
  for (int i = tid; i < 32*300; i += 256) {
    int row = i / 300, o = i - row*300;
    int t = o / 6, k = o - t*6;
    xch[(t*32+row)*8 + k] = bfc(eg[row*3000 + o]);
  }
  for (int i = tid; i < 32*SEQ; i += 256) {
    xch[i*8+6] = (__bf16)1.0f;
    xch[i*8+7] = (__bf16)0.0f;
  }
  for (int i = tid; i < 1024; i += 256) {      // zero hb0[0][*], hb1[0][*]
    ((uint32_t*)hb0[0])[i] = 0u;
    ((uint32_t*)hb1[0])[i] = 0u;
  }

  auto stageWx0 = [&](const float* W, int Kin, const float* bi, const float* bh) {
    for (int i = tid; i < 272; i += 256) {
      int w2 = i / 68, rem = i - w2*68;
      int g = rem / 17, row = rem - g*17;
      __bf16* dst = wx0s + i*8;
      if (row < 16) {
        int gate = (g*4 + w2)*16 + row;
        float gs = (g==2) ? 2.885390082f : -1.442695041f;
        for (int j = 0; j < 8; ++j) {
          float v = 0.f;
          if (j < Kin) v = W[gate*Kin + j];
          else if (j == 6) v = bi[gate] + bh[gate];
          dst[j] = bfc(gs*v);
        }
      } else {
        for (int j = 0; j < 8; ++j) dst[j] = (__bf16)0.f;
      }
    }
  };
  auto stageBc1 = [&](const float* bi, const float* bh) {
    for (int i = tid; i < 256; i += 256) {
      int w2 = i >> 6, g = (i >> 4) & 3, q2 = (i >> 2) & 3, r = i & 3;
      int gate = (g*4 + w2)*16 + q2*4 + r;
      float gs = (g==2) ? 2.885390082f : -1.442695041f;
      bC1[i] = gs*(bi[gate] + bh[gate]);
    }
  };

  bf16x8 whL0[4][2], wxL1[4][2], whL1[4][2];
  auto loadFull = [&](const float* W, bf16x8 (*dst)[2]) {
#pragma unroll
    for (int g = 0; g < 4; ++g)
#pragma unroll
      for (int kc = 0; kc < 2; ++kc) {
        const float* p = W + ((g*4 + w)*16 + c)*64 + kc*32 + q*8;
        f32x4 a = *(const f32x4*)p;
        f32x4 b = *(const f32x4*)(p + 4);
        bf16x8 f;
        f[0]=bfc(GS[g]*a[0]); f[1]=bfc(GS[g]*a[1]);
        f[2]=bfc(GS[g]*a[2]); f[3]=bfc(GS[g]*a[3]);
        f[4]=bfc(GS[g]*b[0]); f[5]=bfc(GS[g]*b[1]);
        f[6]=bfc(GS[g]*b[2]); f[7]=bfc(GS[g]*b[3]);
        dst[g][kc] = f;
      }
  };

  // epilogue write address: hidden u = 16w + q*4 + r, r=0..3 contiguous j
  const int wconst = (w>>1)*512 + (((w&1)<<1) | (q>>1))*128 + c*8 + (q&1)*4;

  float cs0[2][4], cs1[2][4];
#pragma unroll
  for (int gp = 0; gp < 2; ++gp)
#pragma unroll
    for (int i = 0; i < 4; ++i) { cs0[gp][i] = 0.f; cs1[gp][i] = 0.f; }

  auto epilogue = [&](f32x4* a, float* cs, __bf16* hnxt) {
    bf16x4 hv;
#pragma unroll
    for (int r = 0; r < 4; ++r) {
      float eI = ex2(a[0][r]);          // e^{-i}
      float eF = ex2(a[1][r]);          // e^{-f}
      float eG = ex2(a[2][r]);          // e^{2g}
      float eO = ex2(a[3][r]);          // e^{-o}
      float P  = (1.f+eI)*(eG+1.f);
      float tt = 1.f+eF;
      float D  = frcp_(tt*P);
      float c2 = (cs[r]*P + (eG-1.f)*tt)*D;
      float eC = ex2(2.885390082f*c2);
      float h2 = (eC-1.f)*frcp_((1.f+eO)*(eC+1.f));
      cs[r] = c2;
      hv[r] = bfc(h2);
    }
    *(bf16x4*)(hnxt + wconst) = hv;     // one 8B packed write, NO barrier here
  };

  // ---- encoder ----
  stageWx0(eWih0, 6, ebih0, ebhh0);
  stageBc1(ebih1, ebhh1);
  loadFull(eWhh0, whL0);
  loadFull(eWih1, wxL1);
  loadFull(eWhh1, whL1);
  __syncthreads();

  f32x4 acc0[2][4];
#pragma unroll
  for (int gp = 0; gp < 2; ++gp) { // t=0 cellP: h0_{-1}=0 -> x-MFMA only
    bf16x8 xf = zfrag;
    if (q == 0) xf = *(const bf16x8*)(xch + gp*128 + c*8);
#pragma unroll
    for (int g = 0; g < 4; ++g) {
      bf16x8 wxf = *(const bf16x8*)(wx0s + ((w*4+g)*17 + rsel)*8);
      acc0[gp][g] = __builtin_amdgcn_mfma_f32_16x16x32_bf16(wxf, xf, zero4, 0,0,0);
    }
  }

  int pc = 0;
#pragma unroll 1
  for (int t = 0; t < SEQ; ++t) {
    f32x4 acc1[2][4];
    // interval 1: L1 h-part MFMAs (both groups) overlap epilogue0 VALU
#pragma unroll
    for (int gp = 0; gp < 2; ++gp) {
      const __bf16* h1p = hb1[pc][gp];
      bf16x8 hf0 = *(const bf16x8*)(h1p + lane*8);
      bf16x8 hf1 = *(const bf16x8*)(h1p + 512 + lane*8);
#pragma unroll
      for (int g = 0; g < 4; ++g) {
        f32x4 bi4 = *(const f32x4*)(bC1 + w*64 + g*16 + q*4);
        acc1[gp][g] = __builtin_amdgcn_mfma_f32_16x16x32_bf16(whL1[g][0], hf0, bi4, 0,0,0);
      }
#pragma unroll
      for (int g = 0; g < 4; ++g)
        acc1[gp][g] = __builtin_amdgcn_mfma_f32_16x16x32_bf16(whL1[g][1], hf1, acc1[gp][g], 0,0,0);
    }
#pragma unroll
    for (int gp = 0; gp < 2; ++gp)
      epilogue(acc0[gp], cs0[gp], hb0[pc^1][gp]);   // -> h0_t
    __syncthreads();
    // interval 2: finish L1, then prefire next step's full L0 before barrier
    bf16x8 xf0[2], xf1[2];
#pragma unroll
    for (int gp = 0; gp < 2; ++gp) {
      const __bf16* h0n = hb0[pc^1][gp];
      xf0[gp] = *(const bf16x8*)(h0n + lane*8);
      xf1[gp] = *(const bf16x8*)(h0n + 512 + lane*8);
    }
#pragma unroll
    for (int gp = 0; gp < 2; ++gp) {
#pragma unroll
      for (int g = 0; g < 4; ++g)
        acc1[gp][g] = __builtin_amdgcn_mfma_f32_16x16x32_bf16(wxL1[g][0], xf0[gp], acc1[gp][g], 0,0,0);
#pragma unroll
      for (int g = 0; g < 4; ++g)
        acc1[gp][g] = __builtin_amdgcn_mfma_f32_16x16x32_bf16(wxL1[g][1], xf1[gp], acc1[gp][g], 0,0,0);
    }
#pragma unroll
    for (int gp = 0; gp < 2; ++gp)
      epilogue(acc1[gp], cs1[gp], hb1[pc^1][gp]);   // -> h1_t
    if (t + 1 < SEQ) {                  // next-step L0 prefire (both groups)
#pragma unroll
      for (int gp = 0; gp < 2; ++gp) {
        bf16x8 xf = zfrag;
        if (q == 0) xf = *(const bf16x8*)(xch + (t+1)*256 + gp*128 + c*8);
#pragma unroll
        for (int g = 0; g < 4; ++g) {
          bf16x8 wxf = *(const bf16x8*)(wx0s + ((w*4+g)*17 + rsel)*8);
          acc0[gp][g] = __builtin_amdgcn_mfma_f32_16x16x32_bf16(wxf, xf, zero4, 0,0,0);
        }
#pragma unroll
        for (int g = 0; g < 4; ++g)
          acc0[gp][g] = __builtin_amdgcn_mfma_f32_16x16x32_bf16(whL0[g][0], xf0[gp], acc0[gp][g], 0,0,0);
#pragma unroll
        for (int g = 0; g < 4; ++g)
          acc0[gp][g] = __builtin_amdgcn_mfma_f32_16x16x32_bf16(whL0[g][1], xf1[gp], acc0[gp][g], 0,0,0);
      }
    }
    __syncthreads();
    pc ^= 1;
  }

  // ---- decoder setup ----
  stageWx0(dWih0, 2, dbih0, dbhh0);
  stageBc1(dbih1, dbhh1);
  loadFull(dWhh0, whL0);
  loadFull(dWih1, wxL1);
  loadFull(dWhh1, whL1);
  for (int i = tid; i < 24; i += 256) {
    int kc = i / 12, rem = i - kc*12;
    int row = rem / 4, q2 = rem - row*4;
    __bf16* dst = wlc + i*8;
    for (int j = 0; j < 8; ++j)
      dst[j] = (row < 2) ? bfc(linW[row*64 + kc*32 + q2*8 + j]) : (__bf16)0.f;
  }
  const float lb0 = linb[0], lb1 = linb[1];
  const float s0 = stok[0], s1 = stok[1];
  __syncthreads();

  float* obf = (float*)xch;             // alias: xch dead after encoder
  bf16x8 xdec[2];
#pragma unroll
  for (int gp = 0; gp < 2; ++gp) {
    xdec[gp] = zfrag;
    if (q == 0) { xdec[gp][0] = bfc(s0); xdec[gp][1] = bfc(s1); xdec[gp][6] = (__bf16)1.0f; }
  }
#pragma unroll
  for (int gp = 0; gp < 2; ++gp) { // decoder prologue acc0 (x=start, h=h0_enc)
    const __bf16* h0p = hb0[pc][gp];
    bf16x8 hf0 = *(const bf16x8*)(h0p + lane*8);
    bf16x8 hf1 = *(const bf16x8*)(h0p + 512 + lane*8);
#pragma unroll
    for (int g = 0; g < 4; ++g) {
      bf16x8 wxf = *(const bf16x8*)(wx0s + ((w*4+g)*17 + rsel)*8);
      acc0[gp][g] = __builtin_amdgcn_mfma_f32_16x16x32_bf16(wxf, xdec[gp], zero4, 0,0,0);
    }
#pragma unroll
    for (int g = 0; g < 4; ++g)
      acc0[gp][g] = __builtin_amdgcn_mfma_f32_16x16x32_bf16(whL0[g][0], hf0, acc0[gp][g], 0,0,0);
#pragma unroll
    for (int g = 0; g < 4; ++g)
      acc0[gp][g] = __builtin_amdgcn_mfma_f32_16x16x32_bf16(whL0[g][1], hf1, acc0[gp][g], 0,0,0);
  }

  // ---- decoder ----
#pragma unroll 1
  for (int t = 0; t < TDEC; ++t) {
    f32x4 acc1[2][4];
#pragma unroll
    for (int gp = 0; gp < 2; ++gp) {
      const __bf16* h1p = hb1[pc][gp];
      bf16x8 hf0 = *(const bf16x8*)(h1p + lane*8);
      bf16x8 hf1 = *(const bf16x8*)(h1p + 512 + lane*8);
#pragma unroll
      for (int g = 0; g < 4; ++g) {
        f32x4 bi4 = *(const f32x4*)(bC1 + w*64 + g*16 + q*4);
        acc1[gp][g] = __builtin_amdgcn_mfma_f32_16x16x32_bf16(whL1[g][0], hf0, bi4, 0,0,0);
      }
#pragma unroll
      for (int g = 0; g < 4; ++g)
        acc1[gp][g] = __builtin_amdgcn_mfma_f32_16x16x32_bf16(whL1[g][1], hf1, acc1[gp][g], 0,0,0);
    }
#pragma unroll
    for (int gp = 0; gp < 2; ++gp)
      epilogue(acc0[gp], cs0[gp], hb0[pc^1][gp]);
    __syncthreads();
    bf16x8 xf0[2], xf1[2];
#pragma unroll
    for (int gp = 0; gp < 2; ++gp) {
      const __bf16* h0n = hb0[pc^1][gp];
      xf0[gp] = *(const bf16x8*)(h0n + lane*8);
      xf1[gp] = *(const bf16x8*)(h0n + 512 + lane*8);
    }
#pragma unroll
    for (int gp = 0; gp < 2; ++gp) {
#pragma unroll
      for (int g = 0; g < 4; ++g)
        acc1[gp][g] = __builtin_amdgcn_mfma_f32_16x16x32_bf16(wxL1[g][0], xf0[gp], acc1[gp][g], 0,0,0);
#pragma unroll
      for (int g = 0; g < 4; ++g)
        acc1[gp][g] = __builtin_amdgcn_mfma_f32_16x16x32_bf16(wxL1[g][1], xf1[gp], acc1[gp][g], 0,0,0);
    }
#pragma unroll
    for (int gp = 0; gp < 2; ++gp)
      epilogue(acc1[gp], cs1[gp], hb1[pc^1][gp]);
    if (t + 1 < TDEC) {                 // next-step L0 h-part (x waits for head)
#pragma unroll
      for (int gp = 0; gp < 2; ++gp) {
#pragma unroll
        for (int g = 0; g < 4; ++g)
          acc0[gp][g] = __builtin_amdgcn_mfma_f32_16x16x32_bf16(whL0[g][0], xf0[gp], zero4, 0,0,0);
#pragma unroll
        for (int g = 0; g < 4; ++g)
          acc0[gp][g] = __builtin_amdgcn_mfma_f32_16x16x32_bf16(whL0[g][1], xf1[gp], acc0[gp][g], 0,0,0);
      }
    }
    __syncthreads();
    // head: redundant in ALL waves -> feedback stays in registers, no 3rd barrier
#pragma unroll
    for (int gp = 0; gp < 2; ++gp) {
      const __bf16* h1n = hb1[pc^1][gp];
      bf16x8 xh0 = *(const bf16x8*)(h1n + lane*8);
      bf16x8 xh1 = *(const bf16x8*)(h1n + 512 + lane*8);
      int hr = (c < 2) ? c : 2;
      bf16x8 wl0 = *(const bf16x8*)(wlc + hr*32 + q*8);
      bf16x8 wl1 = *(const bf16x8*)(wlc + 96 + hr*32 + q*8);
      f32x4 oa = __builtin_amdgcn_mfma_f32_16x16x32_bf16(wl0, xh0, zero4, 0,0,0);
      oa = __builtin_amdgcn_mfma_f32_16x16x32_bf16(wl1, xh1, oa, 0,0,0);
      if (q == 0) {                     // rows m=0,1 live in quad 0, regs 0,1
        float v0 = oa[0] + lb0, v1 = oa[1] + lb1;
        if (w == 0) {
          f32x2 vv; vv[0] = v0; vv[1] = v1;
          *(f32x2*)(obf + (gp*16+c)*124 + t*2) = vv;   // LDS staging
        }
        xdec[gp][0] = bfc(v0); xdec[gp][1] = bfc(v1);
      }
    }
    if (t + 1 < TDEC) {                 // finish next acc0 with x-MFMA
#pragma unroll
      for (int gp = 0; gp < 2; ++gp)
#pragma unroll
        for (int g = 0; g < 4; ++g) {
          bf16x8 wxf = *(const bf16x8*)(wx0s + ((w*4+g)*17 + rsel)*8);
          acc0[gp][g] = __builtin_amdgcn_mfma_f32_16x16x32_bf16(wxf, xdec[gp], acc0[gp][g], 0,0,0);
        }
    }
    pc ^= 1;
  }

  // ---- coalesced output flush (32 rows) ----
  __syncthreads();
  for (int i = tid; i < 960; i += 256) {
    int row = i / 30;
    int j = (i - row*30) * 4;
    f32x4 v = *(const f32x4*)(obf + row*124 + j);
    *(f32x4*)(out + rowbase*120 + i*4) = v;
  }
}

extern "C" void kernel_launch(void* const* d_in, const int* in_sizes, int n_in,
                              void* d_out, int out_size, void* d_ws, size_t ws_size,
                              hipStream_t stream) {
  (void)in_sizes; (void)n_in; (void)d_ws; (void)ws_size; (void)out_size;
  const float* p[20];
  for (int i = 0; i < 20; ++i) p[i] = (const float*)d_in[i];
  dim3 grid(1024), block(256);
  hipLaunchKernelGGL(lstm_s2s, grid, block, 0, stream,
                     p[0], p[1], p[2], p[3], p[4], p[5], p[6], p[7], p[8], p[9],
                     p[10], p[11], p[12], p[13], p[14], p[15], p[16], p[17], p[18], p[19],
                     (float*)d_out);
}